// Round 17
// baseline (177.539 us; speedup 1.0000x reference)
//
#include <hip/hip_runtime.h>
#include <hip/hip_bf16.h>

#define BATCH 8
#define SEQ   2048
#define CDIM  1024
#define HDIM  64
#define NROWS (BATCH*SEQ)   // 16384
#define NSPLIT 8

typedef __attribute__((ext_vector_type(8))) short bf16x8;
typedef __attribute__((ext_vector_type(4))) float f32x4;

// 0.125 (1/sqrt(64)) * log2(e) — folded into Wq so QK^T emerges in exp2 units
#define QSCALE 0.18033688011112042f
// fixed softmax shift (exp2 units): scores bounded ~±8 << 24.  softmax is
// shift-invariant -> partials ADDITIVE (validated R6-R16: absmax 0.0156) ->
// merge = plain sums over per-split buffers, now fused into attn's tail via
// last-block-merge (one device-scope atomicAdd per block).
#define SFIX 24.0f

__device__ inline ushort f2bf(float f) {
    union { float f; uint u; } x; x.f = f;
    uint r = (x.u + 0x7fffu + ((x.u >> 16) & 1u)) >> 16;
    return (ushort)r;
}

// ---------------------------------------------------------------------------
// Kernel 0: pack W^T into bf16  wp[192][1024].  Coalesced: stage W[c][n]
// fp32 rows into LDS (transposed, padded stride 132), write wp[n][c] rows
// coalesced.  24 blocks = 3 matrices x 8 c-blocks.
// ---------------------------------------------------------------------------
__global__ __launch_bounds__(256) void wpack_kernel(
    const float* __restrict__ Wq, const float* __restrict__ Wk,
    const float* __restrict__ Wv, ushort* __restrict__ wp)
{
    __shared__ ushort lt[64][132];
    const int which = blockIdx.x >> 3;         // 0..2
    const int cblk  = blockIdx.x & 7;          // 0..7
    const float* W = (which == 0) ? Wq : (which == 1) ? Wk : Wv;
    const float sc = (which == 0) ? QSCALE : 1.0f;
    const int t = threadIdx.x;
    const float4* Wb = reinterpret_cast<const float4*>(W + (size_t)cblk * 128 * 64);
    #pragma unroll
    for (int j = 0; j < 8; ++j) {
        const int off4 = j * 256 + t;          // 0..2047
        float4 v = Wb[off4];
        const int c = off4 >> 4;               // 0..127
        const int n0 = (off4 & 15) * 4;        // 0..60
        lt[n0 + 0][c] = f2bf(v.x * sc);
        lt[n0 + 1][c] = f2bf(v.y * sc);
        lt[n0 + 2][c] = f2bf(v.z * sc);
        lt[n0 + 3][c] = f2bf(v.w * sc);
    }
    __syncthreads();
    const int n = t >> 2, cq = (t & 3) * 32;
    ushort* dst = wp + (size_t)(which * 64 + n) * CDIM + cblk * 128 + cq;
    #pragma unroll
    for (int k = 0; k < 32; ++k) dst[k] = lt[n][cq + k];
}

// ---------------------------------------------------------------------------
// Kernel 1: QKV GEMM — exact R13 K-loop (R16's lgkm-only barrier regressed;
// reverted to __syncthreads).  Also zeroes the 128 pair-counters used by the
// fused attn merge (block 0; gemm completes before attn in stream order, so
// counters are 0 every replay without an in-graph memset).
// BM=32 -> 512 blocks (2/CU); 512 thr = 8 waves = 2 rowg x 4 colg.
// ---------------------------------------------------------------------------
__global__ __launch_bounds__(512, 4) void qkv_gemm(
    const float* __restrict__ x, const ushort* __restrict__ wp,
    ushort* __restrict__ qb, ushort* __restrict__ kbuf, ushort* __restrict__ vt,
    uint* __restrict__ cnt)
{
    __shared__ ushort xs[2][32 * 64];    // 8KB   [row][c] bf16, XOR-swizzled
    __shared__ ushort ws[2][192 * 64];   // 48KB  [n][c]  bf16, XOR-swizzled
    const int t = threadIdx.x;

    if (blockIdx.x == 0 && t < 128) cnt[t] = 0u;   // reset merge counters

    const int w = t >> 6, lane = t & 63;
    const int l15 = lane & 15, hi = lane >> 4;
    const int rowg = w & 1, colg = w >> 1;
    const int m0 = blockIdx.x * 32;

    f32x4 acc[3];
    #pragma unroll
    for (int i = 0; i < 3; ++i) acc[i] = (f32x4){0.f, 0.f, 0.f, 0.f};

    const int xrow = t >> 4, xc4 = t & 15;
    const int wn0 = t >> 3,          wc0 = t & 7;
    const int wn1 = (t + 512) >> 3,  wc1 = (t + 512) & 7;
    const int wn2 = (t + 1024) >> 3, wc2 = (t + 1024) & 7;

    float4 xra, xrb;
    uint4 wra0, wra1, wra2, wrb0, wrb1, wrb2;

#define LOADS(S, KK)                                                           \
    xr##S = reinterpret_cast<const float4*>(x + (size_t)(m0 + xrow) * CDIM + (KK))[xc4]; \
    wr##S##0 = reinterpret_cast<const uint4*>(wp + (size_t)wn0 * CDIM + (KK))[wc0]; \
    wr##S##1 = reinterpret_cast<const uint4*>(wp + (size_t)wn1 * CDIM + (KK))[wc1]; \
    wr##S##2 = reinterpret_cast<const uint4*>(wp + (size_t)wn2 * CDIM + (KK))[wc2];

#define WRITES(S, BUF)                                                         \
    {                                                                          \
        ushort4 bx = make_ushort4(f2bf(xr##S.x), f2bf(xr##S.y), f2bf(xr##S.z), f2bf(xr##S.w)); \
        int xb = (xrow * 128 + xc4 * 8) ^ ((xrow & 7) << 4);                   \
        *reinterpret_cast<ushort4*>(reinterpret_cast<char*>(xs[BUF]) + xb) = bx; \
        int y0 = (wn0 * 128 + wc0 * 16) ^ ((wn0 & 7) << 4);                    \
        int y1 = (wn1 * 128 + wc1 * 16) ^ ((wn1 & 7) << 4);                    \
        int y2 = (wn2 * 128 + wc2 * 16) ^ ((wn2 & 7) << 4);                    \
        *reinterpret_cast<uint4*>(reinterpret_cast<char*>(ws[BUF]) + y0) = wr##S##0; \
        *reinterpret_cast<uint4*>(reinterpret_cast<char*>(ws[BUF]) + y1) = wr##S##1; \
        *reinterpret_cast<uint4*>(reinterpret_cast<char*>(ws[BUF]) + y2) = wr##S##2; \
    }

#define MFMA_STEP(BUF)                                                         \
    {                                                                          \
        const int arow = rowg * 16 + l15;                                      \
        _Pragma("unroll")                                                      \
        for (int c32 = 0; c32 < 2; ++c32) {                                    \
            const int abyte = (arow * 128 + hi * 16 + c32 * 64) ^ ((arow & 7) << 4); \
            bf16x8 a = *reinterpret_cast<const bf16x8*>(reinterpret_cast<char*>(xs[BUF]) + abyte); \
            _Pragma("unroll")                                                  \
            for (int nf = 0; nf < 3; ++nf) {                                   \
                const int n = colg * 48 + nf * 16 + l15;                       \
                const int bbyte = (n * 128 + hi * 16 + c32 * 64) ^ ((n & 7) << 4); \
                bf16x8 b = *reinterpret_cast<const bf16x8*>(reinterpret_cast<char*>(ws[BUF]) + bbyte); \
                acc[nf] = __builtin_amdgcn_mfma_f32_16x16x32_bf16(a, b, acc[nf], 0, 0, 0); \
            }                                                                  \
        }                                                                      \
    }

    LOADS(a, 0)
    LOADS(b, 64)
    WRITES(a, 0)
    __syncthreads();

    for (int step = 0; step < 16; step += 2) {
        if (step + 2 < 16) { LOADS(a, (step + 2) * 64) }
        MFMA_STEP(0)
        WRITES(b, 1)
        __syncthreads();
        if (step + 3 < 16) { LOADS(b, (step + 3) * 64) }
        MFMA_STEP(1)
        if (step + 2 < 16) { WRITES(a, 0) }
        __syncthreads();
    }
#undef LOADS
#undef WRITES
#undef MFMA_STEP

    #pragma unroll
    for (int nf = 0; nf < 3; ++nf) {
        const int n = colg * 48 + nf * 16 + l15;
        #pragma unroll
        for (int r = 0; r < 4; ++r) {
            const int grow = m0 + rowg * 16 + hi * 4 + r;
            const ushort bv = f2bf(acc[nf][r]);
            if (n < 64) {
                qb[(size_t)grow * 64 + n] = bv;
            } else if (n < 128) {
                kbuf[(size_t)grow * 64 + (n - 64)] = bv;
            } else {
                const int b = grow >> 11, tt = grow & 2047;
                vt[(((size_t)b * 64 + (n - 128)) << 11) + tt] = bv;
            }
        }
    }
}

// ---------------------------------------------------------------------------
// Kernel 2: flash attention (R13 loop, byte-identical; 16.6us measured) with
// the MERGE FUSED into the tail: after a block's final DUMP it does
// threadfence -> syncthreads -> thread0 atomicAdd on its pair's counter
// (standard release pattern); the 8th arrival merges the pair's 128 rows
// from the 8 partial buffers and writes `out`.  One atomic per block.
// ---------------------------------------------------------------------------
__global__ __launch_bounds__(256, 4) void attn_flash(
    const ushort* __restrict__ qb, const ushort* __restrict__ kbuf,
    const ushort* __restrict__ vt, ushort* __restrict__ Opart,
    float* __restrict__ lpart, float* __restrict__ out,
    uint* __restrict__ cnt)
{
    __shared__ ushort kst[2][64 * 64];   // 16KB  K tile, XOR-swizzled
    __shared__ ushort vst[2][64 * 64];   // 16KB  V tile (vt layout [d][t])
    __shared__ ushort P[4][1024];        // 8KB   per-wave P round-trip
    __shared__ int lastFlag;

    const int t = threadIdx.x;
    const int w = t >> 6, lane = t & 63;
    const int l15 = lane & 15, hi = lane >> 4;
    const int bid = blockIdx.x;
    const int pid = (bid & 7) * 128 + (bid >> 3);   // XCD x -> batch x
    const int batch = pid >> 7;
    const int rem = pid & 127;
    const int pairIdx = rem >> 3;        // 0..15
    const int s = rem & 7;               // split 0..7
    const int qtA = pairIdx, qtB = 31 - pairIdx;    // 64-row q-tiles
    const int ntA = qtA + 1;             // ntA + ntB == 33

    const ushort* kB = kbuf + (size_t)batch * SEQ * 64;
    const ushort* vB = vt + (size_t)batch * 64 * SEQ;
    ushort* Osp = Opart + (size_t)s * NROWS * 64;
    float* lsp = lpart + (size_t)s * NROWS;
    char* pw = reinterpret_cast<char*>(P[w]);

    const int r0 = t >> 3, c8 = t & 7;   // chunk0 row 0..31
    const int r1 = r0 + 32;              // chunk1 row 32..63
    const int sb0 = (r0 * 128 + c8 * 16) ^ ((r0 & 7) << 4);
    const int sb1 = (r1 * 128 + c8 * 16) ^ ((r1 & 7) << 4);

    uint4 kr0, kr1, vr0, vr1;

#define STAGE_ISSUE(C)                                                        \
    {                                                                         \
        const int kt_ = ((C) >= ntA) ? ((C) - ntA) : (C);                     \
        const int j0_ = kt_ * 64;                                             \
        kr0 = *reinterpret_cast<const uint4*>(kB + (size_t)(j0_ + r0) * 64 + c8 * 8); \
        kr1 = *reinterpret_cast<const uint4*>(kB + (size_t)(j0_ + r1) * 64 + c8 * 8); \
        vr0 = *reinterpret_cast<const uint4*>(vB + (size_t)r0 * SEQ + j0_ + c8 * 8);  \
        vr1 = *reinterpret_cast<const uint4*>(vB + (size_t)r1 * SEQ + j0_ + c8 * 8);  \
    }

#define STAGE_WRITE(BUF)                                                      \
    {                                                                         \
        *reinterpret_cast<uint4*>(reinterpret_cast<char*>(kst[BUF]) + sb0) = kr0; \
        *reinterpret_cast<uint4*>(reinterpret_cast<char*>(kst[BUF]) + sb1) = kr1; \
        *reinterpret_cast<uint4*>(reinterpret_cast<char*>(vst[BUF]) + sb0) = vr0; \
        *reinterpret_cast<uint4*>(reinterpret_cast<char*>(vst[BUF]) + sb1) = vr1; \
    }

#define LOADQ(QT)                                                             \
    {                                                                         \
        const ushort* qp_ = qb + (size_t)(batch * SEQ + (QT) * 64 + w * 16 + l15) * 64 + hi * 8; \
        aq0 = *reinterpret_cast<const bf16x8*>(qp_);                          \
        aq1 = *reinterpret_cast<const bf16x8*>(qp_ + 32);                     \
    }

#define DUMP(QT)                                                              \
    {                                                                         \
        _Pragma("unroll")                                                     \
        for (int dt = 0; dt < 4; ++dt)                                        \
            _Pragma("unroll")                                                 \
            for (int r = 0; r < 4; ++r)                                       \
                Osp[(size_t)(batch * SEQ + (QT) * 64 + w * 16 + hi * 4 + r) * 64 + dt * 16 + l15] = f2bf(O[dt][r]); \
        _Pragma("unroll")                                                     \
        for (int r = 0; r < 4; ++r) {                                         \
            float s_ = lsum[r];                                               \
            s_ += __shfl_xor(s_, 1, 64);                                      \
            s_ += __shfl_xor(s_, 2, 64);                                      \
            s_ += __shfl_xor(s_, 4, 64);                                      \
            s_ += __shfl_xor(s_, 8, 64);                                      \
            if (l15 == 0)                                                     \
                lsp[batch * SEQ + (QT) * 64 + w * 16 + hi * 4 + r] = s_;      \
        }                                                                     \
    }

#define RESET_STATE()                                                         \
    {                                                                         \
        _Pragma("unroll")                                                     \
        for (int i = 0; i < 4; ++i) {                                         \
            O[i] = (f32x4){0.f, 0.f, 0.f, 0.f};                               \
            lsum[i] = 0.f;                                                    \
        }                                                                     \
    }

    bf16x8 aq0, aq1;
    LOADQ(qtA)
    f32x4 O[4];
    float lsum[4];
    RESET_STATE()

    STAGE_ISSUE(s)
    STAGE_WRITE(0)
    __syncthreads();

    int curB = 0, cur = 0;
    for (int c = s; c < 33; c += 8) {
        if (c + 8 < 33) { STAGE_ISSUE(c + 8) }    // in flight over compute
        if (c >= ntA && !curB) {                  // block-uniform A -> B
            DUMP(qtA)
            RESET_STATE()
            LOADQ(qtB)
            curB = 1;
        }
        const int qt = curB ? qtB : qtA;
        const int kt = curB ? (c - ntA) : c;
        const int j0 = kt * 64;
        const int qrow0 = qt * 64 + w * 16;
        const bool diag = curB ? (c == 32) : (c == ntA - 1);

        const char* kc = reinterpret_cast<const char*>(kst[cur]);
        const char* vc = reinterpret_cast<const char*>(vst[cur]);

        // ---- QK^T from LDS K ----
        f32x4 S[4];
        #pragma unroll
        for (int kb = 0; kb < 4; ++kb) {
            const int key = kb * 16 + l15;
            const int sw = (key & 7) << 4;
            bf16x8 b0 = *reinterpret_cast<const bf16x8*>(kc + ((key * 128 + hi * 16) ^ sw));
            bf16x8 b1 = *reinterpret_cast<const bf16x8*>(kc + ((key * 128 + hi * 16 + 64) ^ sw));
            f32x4 z = (f32x4){0.f, 0.f, 0.f, 0.f};
            z = __builtin_amdgcn_mfma_f32_16x16x32_bf16(aq0, b0, z, 0, 0, 0);
            z = __builtin_amdgcn_mfma_f32_16x16x32_bf16(aq1, b1, z, 0, 0, 0);
            S[kb] = z;
        }
        // ---- causal mask: only the diagonal tile ----
        if (diag) {
            #pragma unroll
            for (int kb = 0; kb < 4; ++kb) {
                const int key = j0 + kb * 16 + l15;
                #pragma unroll
                for (int r = 0; r < 4; ++r) {
                    const int qr = qrow0 + hi * 4 + r;
                    if (key > qr) S[kb][r] = -1e30f;
                }
            }
        }
        // ---- fixed-shift softmax ----
        #pragma unroll
        for (int kb = 0; kb < 4; ++kb)
            #pragma unroll
            for (int r = 0; r < 4; ++r)
                S[kb][r] = exp2f(S[kb][r] - SFIX);
        #pragma unroll
        for (int r = 0; r < 4; ++r)
            lsum[r] += (S[0][r] + S[1][r]) + (S[2][r] + S[3][r]);

        // ---- P: C-layout -> per-wave LDS (swizzled) -> A-layout ----
        #pragma unroll
        for (int kb = 0; kb < 4; ++kb) {
            #pragma unroll
            for (int r = 0; r < 4; ++r) {
                const int prow = hi * 4 + r;
                const int pcol = kb * 16 + l15;
                const int byte = (prow * 128 + pcol * 2) ^ ((prow & 7) << 4);
                *reinterpret_cast<ushort*>(pw + byte) = f2bf(S[kb][r]);
            }
        }
        asm volatile("" ::: "memory");   // intra-wave LDS in-order
        const int pb0 = (l15 * 128 + hi * 16) ^ ((l15 & 7) << 4);
        const int pb1 = (l15 * 128 + hi * 16 + 64) ^ ((l15 & 7) << 4);
        bf16x8 pa0 = *reinterpret_cast<const bf16x8*>(pw + pb0);
        bf16x8 pa1 = *reinterpret_cast<const bf16x8*>(pw + pb1);
        // ---- PV from LDS V ----
        #pragma unroll
        for (int dt = 0; dt < 4; ++dt) {
            const int d = dt * 16 + l15;
            const int sw = (d & 7) << 4;
            bf16x8 v0 = *reinterpret_cast<const bf16x8*>(vc + ((d * 128 + hi * 16) ^ sw));
            bf16x8 v1 = *reinterpret_cast<const bf16x8*>(vc + ((d * 128 + hi * 16 + 64) ^ sw));
            O[dt] = __builtin_amdgcn_mfma_f32_16x16x32_bf16(pa0, v0, O[dt], 0, 0, 0);
            O[dt] = __builtin_amdgcn_mfma_f32_16x16x32_bf16(pa1, v1, O[dt], 0, 0, 0);
        }
        if (c + 8 < 33) { STAGE_WRITE(cur ^ 1) }
        __syncthreads();
        cur ^= 1;
    }

    DUMP(qtB)    // curB==1 always on exit
#undef STAGE_ISSUE
#undef STAGE_WRITE
#undef LOADQ
#undef DUMP
#undef RESET_STATE

    // ---- fused merge: last of the pair's 8 split-blocks merges ----
    __threadfence();                     // release this thread's partials
    __syncthreads();                     // all threads' fences done
    if (t == 0) {
        const uint old = atomicAdd(&cnt[batch * 16 + pairIdx], 1u);
        lastFlag = (old == 7u) ? 1 : 0;
    }
    __syncthreads();
    if (lastFlag) {
        __threadfence();                 // acquire: order reads after the atomic
        // tasks: 2 tiles x 64 rows x 8 col-groups (uint4 = 8 bf16 cols) = 1024
        for (int task = t; task < 1024; task += 256) {
            const int tile = task >> 9;
            const int row  = (task >> 3) & 63;
            const int cg   = task & 7;
            const int qt   = tile ? qtB : qtA;
            const int grow = batch * SEQ + qt * 64 + row;
            float acc[8] = {0.f, 0.f, 0.f, 0.f, 0.f, 0.f, 0.f, 0.f};
            float lv = 0.f;
            #pragma unroll
            for (int s2 = 0; s2 < NSPLIT; ++s2) {
                const uint4 v = *reinterpret_cast<const uint4*>(
                    Opart + ((size_t)s2 * NROWS + grow) * 64 + cg * 8);
                const uint u0 = v.x, u1 = v.y, u2 = v.z, u3 = v.w;
                acc[0] += __uint_as_float((u0 & 0xffffu) << 16);
                acc[1] += __uint_as_float(u0 & 0xffff0000u);
                acc[2] += __uint_as_float((u1 & 0xffffu) << 16);
                acc[3] += __uint_as_float(u1 & 0xffff0000u);
                acc[4] += __uint_as_float((u2 & 0xffffu) << 16);
                acc[5] += __uint_as_float(u2 & 0xffff0000u);
                acc[6] += __uint_as_float((u3 & 0xffffu) << 16);
                acc[7] += __uint_as_float(u3 & 0xffff0000u);
                lv += lpart[s2 * NROWS + grow];
            }
            const float inv = 1.0f / lv;
            float4 o0 = make_float4(acc[0] * inv, acc[1] * inv, acc[2] * inv, acc[3] * inv);
            float4 o1 = make_float4(acc[4] * inv, acc[5] * inv, acc[6] * inv, acc[7] * inv);
            float* op = out + (size_t)grow * 64 + cg * 8;
            *reinterpret_cast<float4*>(op)     = o0;
            *reinterpret_cast<float4*>(op + 4) = o1;
        }
    }
}

extern "C" void kernel_launch(void* const* d_in, const int* in_sizes, int n_in,
                              void* d_out, int out_size, void* d_ws, size_t ws_size,
                              hipStream_t stream) {
    const float* x  = (const float*)d_in[0];
    const float* Wq = (const float*)d_in[1];
    const float* Wk = (const float*)d_in[2];
    const float* Wv = (const float*)d_in[3];
    float* out = (float*)d_out;

    ushort* qb   = (ushort*)d_ws;                    // 2MB
    ushort* kbuf = qb + (size_t)NROWS * 64;          // 2MB
    ushort* vt   = kbuf + (size_t)NROWS * 64;        // 2MB (transposed V)
    ushort* wp   = vt + (size_t)NROWS * 64;          // 384KB packed W^T
    float* lpart = (float*)(wp + 192 * 1024);        // 512KB  8 x row-sums
    ushort* Opart = (ushort*)(lpart + (size_t)NSPLIT * NROWS);  // 16MB  8 x bf16 O partials
    uint* cnt = (uint*)(Opart + (size_t)NSPLIT * NROWS * 64);   // 512B  128 pair-counters

    wpack_kernel<<<24, 256, 0, stream>>>(Wq, Wk, Wv, wp);
    qkv_gemm<<<NROWS / 32, 512, 0, stream>>>(x, wp, qb, kbuf, vt, cnt);
    attn_flash<<<1024, 256, 0, stream>>>(qb, kbuf, vt, Opart, lpart, out, cnt);
}

// Round 18
// 68.720 us; speedup vs baseline: 2.5835x; 2.5835x over previous
//
#include <hip/hip_runtime.h>
#include <hip/hip_bf16.h>

#define BATCH 8
#define SEQ   2048
#define CDIM  1024
#define HDIM  64
#define NROWS (BATCH*SEQ)   // 16384
#define NSPLIT 8

typedef __attribute__((ext_vector_type(8))) short bf16x8;
typedef __attribute__((ext_vector_type(4))) float f32x4;

// 0.125 (1/sqrt(64)) * log2(e) — folded into Wq so QK^T emerges in exp2 units
#define QSCALE 0.18033688011112042f
// fixed softmax shift (exp2 units): scores bounded ~±8 << 24.  softmax is
// shift-invariant -> partials ADDITIVE (validated R6-R17: absmax 0.0156) ->
// cross-block merge = plain sums over per-split buffers (NO atomics; R17
// showed threadfence-based fusion costs ~150us on non-coherent XCD L2s).
#define SFIX 24.0f

__device__ inline ushort f2bf(float f) {
    union { float f; uint u; } x; x.f = f;
    uint r = (x.u + 0x7fffu + ((x.u >> 16) & 1u)) >> 16;
    return (ushort)r;
}

// ---------------------------------------------------------------------------
// Kernel 0: pack W^T into bf16  wp[192][1024].  Coalesced: stage W[c][n]
// fp32 rows into LDS (transposed, padded stride 132), write wp[n][c] rows
// coalesced.  24 blocks = 3 matrices x 8 c-blocks.
// ---------------------------------------------------------------------------
__global__ __launch_bounds__(256) void wpack_kernel(
    const float* __restrict__ Wq, const float* __restrict__ Wk,
    const float* __restrict__ Wv, ushort* __restrict__ wp)
{
    __shared__ ushort lt[64][132];
    const int which = blockIdx.x >> 3;         // 0..2
    const int cblk  = blockIdx.x & 7;          // 0..7
    const float* W = (which == 0) ? Wq : (which == 1) ? Wk : Wv;
    const float sc = (which == 0) ? QSCALE : 1.0f;
    const int t = threadIdx.x;
    const float4* Wb = reinterpret_cast<const float4*>(W + (size_t)cblk * 128 * 64);
    #pragma unroll
    for (int j = 0; j < 8; ++j) {
        const int off4 = j * 256 + t;          // 0..2047
        float4 v = Wb[off4];
        const int c = off4 >> 4;               // 0..127
        const int n0 = (off4 & 15) * 4;        // 0..60
        lt[n0 + 0][c] = f2bf(v.x * sc);
        lt[n0 + 1][c] = f2bf(v.y * sc);
        lt[n0 + 2][c] = f2bf(v.z * sc);
        lt[n0 + 3][c] = f2bf(v.w * sc);
    }
    __syncthreads();
    const int n = t >> 2, cq = (t & 3) * 32;
    ushort* dst = wp + (size_t)(which * 64 + n) * CDIM + cblk * 128 + cq;
    #pragma unroll
    for (int k = 0; k < 32; ++k) dst[k] = lt[n][cq + k];
}

// ---------------------------------------------------------------------------
// Kernel 1: QKV GEMM (R13 exact).  MEASUREMENT ROUND: launched TWICE
// (idempotent — deterministic writes from fixed inputs) so
// gemm = Tnew - 51.4us.  BM=32 -> 512 blocks; 512 thr = 8 waves.
// ---------------------------------------------------------------------------
__global__ __launch_bounds__(512, 4) void qkv_gemm(
    const float* __restrict__ x, const ushort* __restrict__ wp,
    ushort* __restrict__ qb, ushort* __restrict__ kbuf, ushort* __restrict__ vt)
{
    __shared__ ushort xs[2][32 * 64];    // 8KB   [row][c] bf16, XOR-swizzled
    __shared__ ushort ws[2][192 * 64];   // 48KB  [n][c]  bf16, XOR-swizzled
    const int t = threadIdx.x;
    const int w = t >> 6, lane = t & 63;
    const int l15 = lane & 15, hi = lane >> 4;
    const int rowg = w & 1, colg = w >> 1;
    const int m0 = blockIdx.x * 32;

    f32x4 acc[3];
    #pragma unroll
    for (int i = 0; i < 3; ++i) acc[i] = (f32x4){0.f, 0.f, 0.f, 0.f};

    const int xrow = t >> 4, xc4 = t & 15;
    const int wn0 = t >> 3,          wc0 = t & 7;
    const int wn1 = (t + 512) >> 3,  wc1 = (t + 512) & 7;
    const int wn2 = (t + 1024) >> 3, wc2 = (t + 1024) & 7;

    float4 xra, xrb;
    uint4 wra0, wra1, wra2, wrb0, wrb1, wrb2;

#define LOADS(S, KK)                                                           \
    xr##S = reinterpret_cast<const float4*>(x + (size_t)(m0 + xrow) * CDIM + (KK))[xc4]; \
    wr##S##0 = reinterpret_cast<const uint4*>(wp + (size_t)wn0 * CDIM + (KK))[wc0]; \
    wr##S##1 = reinterpret_cast<const uint4*>(wp + (size_t)wn1 * CDIM + (KK))[wc1]; \
    wr##S##2 = reinterpret_cast<const uint4*>(wp + (size_t)wn2 * CDIM + (KK))[wc2];

#define WRITES(S, BUF)                                                         \
    {                                                                          \
        ushort4 bx = make_ushort4(f2bf(xr##S.x), f2bf(xr##S.y), f2bf(xr##S.z), f2bf(xr##S.w)); \
        int xb = (xrow * 128 + xc4 * 8) ^ ((xrow & 7) << 4);                   \
        *reinterpret_cast<ushort4*>(reinterpret_cast<char*>(xs[BUF]) + xb) = bx; \
        int y0 = (wn0 * 128 + wc0 * 16) ^ ((wn0 & 7) << 4);                    \
        int y1 = (wn1 * 128 + wc1 * 16) ^ ((wn1 & 7) << 4);                    \
        int y2 = (wn2 * 128 + wc2 * 16) ^ ((wn2 & 7) << 4);                    \
        *reinterpret_cast<uint4*>(reinterpret_cast<char*>(ws[BUF]) + y0) = wr##S##0; \
        *reinterpret_cast<uint4*>(reinterpret_cast<char*>(ws[BUF]) + y1) = wr##S##1; \
        *reinterpret_cast<uint4*>(reinterpret_cast<char*>(ws[BUF]) + y2) = wr##S##2; \
    }

#define MFMA_STEP(BUF)                                                         \
    {                                                                          \
        const int arow = rowg * 16 + l15;                                      \
        _Pragma("unroll")                                                      \
        for (int c32 = 0; c32 < 2; ++c32) {                                    \
            const int abyte = (arow * 128 + hi * 16 + c32 * 64) ^ ((arow & 7) << 4); \
            bf16x8 a = *reinterpret_cast<const bf16x8*>(reinterpret_cast<char*>(xs[BUF]) + abyte); \
            _Pragma("unroll")                                                  \
            for (int nf = 0; nf < 3; ++nf) {                                   \
                const int n = colg * 48 + nf * 16 + l15;                       \
                const int bbyte = (n * 128 + hi * 16 + c32 * 64) ^ ((n & 7) << 4); \
                bf16x8 b = *reinterpret_cast<const bf16x8*>(reinterpret_cast<char*>(ws[BUF]) + bbyte); \
                acc[nf] = __builtin_amdgcn_mfma_f32_16x16x32_bf16(a, b, acc[nf], 0, 0, 0); \
            }                                                                  \
        }                                                                      \
    }

    LOADS(a, 0)
    LOADS(b, 64)
    WRITES(a, 0)
    __syncthreads();

    for (int step = 0; step < 16; step += 2) {
        if (step + 2 < 16) { LOADS(a, (step + 2) * 64) }
        MFMA_STEP(0)
        WRITES(b, 1)
        __syncthreads();
        if (step + 3 < 16) { LOADS(b, (step + 3) * 64) }
        MFMA_STEP(1)
        if (step + 2 < 16) { WRITES(a, 0) }
        __syncthreads();
    }
#undef LOADS
#undef WRITES
#undef MFMA_STEP

    #pragma unroll
    for (int nf = 0; nf < 3; ++nf) {
        const int n = colg * 48 + nf * 16 + l15;
        #pragma unroll
        for (int r = 0; r < 4; ++r) {
            const int grow = m0 + rowg * 16 + hi * 4 + r;
            const ushort bv = f2bf(acc[nf][r]);
            if (n < 64) {
                qb[(size_t)grow * 64 + n] = bv;
            } else if (n < 128) {
                kbuf[(size_t)grow * 64 + (n - 64)] = bv;
            } else {
                const int b = grow >> 11, tt = grow & 2047;
                vt[(((size_t)b * 64 + (n - 128)) << 11) + tt] = bv;
            }
        }
    }
}

// ---------------------------------------------------------------------------
// Kernel 2: flash attention, LDS-shared K/V (R13 exact; 16.6us measured).
// ---------------------------------------------------------------------------
__global__ __launch_bounds__(256, 4) void attn_flash(
    const ushort* __restrict__ qb, const ushort* __restrict__ kbuf,
    const ushort* __restrict__ vt, ushort* __restrict__ Opart,
    float* __restrict__ lpart)
{
    __shared__ ushort kst[2][64 * 64];   // 16KB  K tile, XOR-swizzled
    __shared__ ushort vst[2][64 * 64];   // 16KB  V tile (vt layout [d][t])
    __shared__ ushort P[4][1024];        // 8KB   per-wave P round-trip

    const int t = threadIdx.x;
    const int w = t >> 6, lane = t & 63;
    const int l15 = lane & 15, hi = lane >> 4;
    const int bid = blockIdx.x;
    const int pid = (bid & 7) * 128 + (bid >> 3);   // XCD x -> batch x
    const int batch = pid >> 7;
    const int rem = pid & 127;
    const int pairIdx = rem >> 3;        // 0..15
    const int s = rem & 7;               // split 0..7
    const int qtA = pairIdx, qtB = 31 - pairIdx;    // 64-row q-tiles
    const int ntA = qtA + 1;             // ntA + ntB == 33

    const ushort* kB = kbuf + (size_t)batch * SEQ * 64;
    const ushort* vB = vt + (size_t)batch * 64 * SEQ;
    ushort* Osp = Opart + (size_t)s * NROWS * 64;
    float* lsp = lpart + (size_t)s * NROWS;
    char* pw = reinterpret_cast<char*>(P[w]);

    const int r0 = t >> 3, c8 = t & 7;   // chunk0 row 0..31
    const int r1 = r0 + 32;              // chunk1 row 32..63
    const int sb0 = (r0 * 128 + c8 * 16) ^ ((r0 & 7) << 4);
    const int sb1 = (r1 * 128 + c8 * 16) ^ ((r1 & 7) << 4);

    uint4 kr0, kr1, vr0, vr1;

#define STAGE_ISSUE(C)                                                        \
    {                                                                         \
        const int kt_ = ((C) >= ntA) ? ((C) - ntA) : (C);                     \
        const int j0_ = kt_ * 64;                                             \
        kr0 = *reinterpret_cast<const uint4*>(kB + (size_t)(j0_ + r0) * 64 + c8 * 8); \
        kr1 = *reinterpret_cast<const uint4*>(kB + (size_t)(j0_ + r1) * 64 + c8 * 8); \
        vr0 = *reinterpret_cast<const uint4*>(vB + (size_t)r0 * SEQ + j0_ + c8 * 8);  \
        vr1 = *reinterpret_cast<const uint4*>(vB + (size_t)r1 * SEQ + j0_ + c8 * 8);  \
    }

#define STAGE_WRITE(BUF)                                                      \
    {                                                                         \
        *reinterpret_cast<uint4*>(reinterpret_cast<char*>(kst[BUF]) + sb0) = kr0; \
        *reinterpret_cast<uint4*>(reinterpret_cast<char*>(kst[BUF]) + sb1) = kr1; \
        *reinterpret_cast<uint4*>(reinterpret_cast<char*>(vst[BUF]) + sb0) = vr0; \
        *reinterpret_cast<uint4*>(reinterpret_cast<char*>(vst[BUF]) + sb1) = vr1; \
    }

#define LOADQ(QT)                                                             \
    {                                                                         \
        const ushort* qp_ = qb + (size_t)(batch * SEQ + (QT) * 64 + w * 16 + l15) * 64 + hi * 8; \
        aq0 = *reinterpret_cast<const bf16x8*>(qp_);                          \
        aq1 = *reinterpret_cast<const bf16x8*>(qp_ + 32);                     \
    }

#define DUMP(QT)                                                              \
    {                                                                         \
        _Pragma("unroll")                                                     \
        for (int dt = 0; dt < 4; ++dt)                                        \
            _Pragma("unroll")                                                 \
            for (int r = 0; r < 4; ++r)                                       \
                Osp[(size_t)(batch * SEQ + (QT) * 64 + w * 16 + hi * 4 + r) * 64 + dt * 16 + l15] = f2bf(O[dt][r]); \
        _Pragma("unroll")                                                     \
        for (int r = 0; r < 4; ++r) {                                         \
            float s_ = lsum[r];                                               \
            s_ += __shfl_xor(s_, 1, 64);                                      \
            s_ += __shfl_xor(s_, 2, 64);                                      \
            s_ += __shfl_xor(s_, 4, 64);                                      \
            s_ += __shfl_xor(s_, 8, 64);                                      \
            if (l15 == 0)                                                     \
                lsp[batch * SEQ + (QT) * 64 + w * 16 + hi * 4 + r] = s_;      \
        }                                                                     \
    }

#define RESET_STATE()                                                         \
    {                                                                         \
        _Pragma("unroll")                                                     \
        for (int i = 0; i < 4; ++i) {                                         \
            O[i] = (f32x4){0.f, 0.f, 0.f, 0.f};                               \
            lsum[i] = 0.f;                                                    \
        }                                                                     \
    }

    bf16x8 aq0, aq1;
    LOADQ(qtA)
    f32x4 O[4];
    float lsum[4];
    RESET_STATE()

    STAGE_ISSUE(s)
    STAGE_WRITE(0)
    __syncthreads();

    int curB = 0, cur = 0;
    for (int c = s; c < 33; c += 8) {
        if (c + 8 < 33) { STAGE_ISSUE(c + 8) }    // in flight over compute
        if (c >= ntA && !curB) {                  // block-uniform A -> B
            DUMP(qtA)
            RESET_STATE()
            LOADQ(qtB)
            curB = 1;
        }
        const int qt = curB ? qtB : qtA;
        const int kt = curB ? (c - ntA) : c;
        const int j0 = kt * 64;
        const int qrow0 = qt * 64 + w * 16;
        const bool diag = curB ? (c == 32) : (c == ntA - 1);

        const char* kc = reinterpret_cast<const char*>(kst[cur]);
        const char* vc = reinterpret_cast<const char*>(vst[cur]);

        // ---- QK^T from LDS K ----
        f32x4 S[4];
        #pragma unroll
        for (int kb = 0; kb < 4; ++kb) {
            const int key = kb * 16 + l15;
            const int sw = (key & 7) << 4;
            bf16x8 b0 = *reinterpret_cast<const bf16x8*>(kc + ((key * 128 + hi * 16) ^ sw));
            bf16x8 b1 = *reinterpret_cast<const bf16x8*>(kc + ((key * 128 + hi * 16 + 64) ^ sw));
            f32x4 z = (f32x4){0.f, 0.f, 0.f, 0.f};
            z = __builtin_amdgcn_mfma_f32_16x16x32_bf16(aq0, b0, z, 0, 0, 0);
            z = __builtin_amdgcn_mfma_f32_16x16x32_bf16(aq1, b1, z, 0, 0, 0);
            S[kb] = z;
        }
        // ---- causal mask: only the diagonal tile ----
        if (diag) {
            #pragma unroll
            for (int kb = 0; kb < 4; ++kb) {
                const int key = j0 + kb * 16 + l15;
                #pragma unroll
                for (int r = 0; r < 4; ++r) {
                    const int qr = qrow0 + hi * 4 + r;
                    if (key > qr) S[kb][r] = -1e30f;
                }
            }
        }
        // ---- fixed-shift softmax ----
        #pragma unroll
        for (int kb = 0; kb < 4; ++kb)
            #pragma unroll
            for (int r = 0; r < 4; ++r)
                S[kb][r] = exp2f(S[kb][r] - SFIX);
        #pragma unroll
        for (int r = 0; r < 4; ++r)
            lsum[r] += (S[0][r] + S[1][r]) + (S[2][r] + S[3][r]);

        // ---- P: C-layout -> per-wave LDS (swizzled) -> A-layout ----
        #pragma unroll
        for (int kb = 0; kb < 4; ++kb) {
            #pragma unroll
            for (int r = 0; r < 4; ++r) {
                const int prow = hi * 4 + r;
                const int pcol = kb * 16 + l15;
                const int byte = (prow * 128 + pcol * 2) ^ ((prow & 7) << 4);
                *reinterpret_cast<ushort*>(pw + byte) = f2bf(S[kb][r]);
            }
        }
        asm volatile("" ::: "memory");   // intra-wave LDS in-order
        const int pb0 = (l15 * 128 + hi * 16) ^ ((l15 & 7) << 4);
        const int pb1 = (l15 * 128 + hi * 16 + 64) ^ ((l15 & 7) << 4);
        bf16x8 pa0 = *reinterpret_cast<const bf16x8*>(pw + pb0);
        bf16x8 pa1 = *reinterpret_cast<const bf16x8*>(pw + pb1);
        // ---- PV from LDS V ----
        #pragma unroll
        for (int dt = 0; dt < 4; ++dt) {
            const int d = dt * 16 + l15;
            const int sw = (d & 7) << 4;
            bf16x8 v0 = *reinterpret_cast<const bf16x8*>(vc + ((d * 128 + hi * 16) ^ sw));
            bf16x8 v1 = *reinterpret_cast<const bf16x8*>(vc + ((d * 128 + hi * 16 + 64) ^ sw));
            O[dt] = __builtin_amdgcn_mfma_f32_16x16x32_bf16(pa0, v0, O[dt], 0, 0, 0);
            O[dt] = __builtin_amdgcn_mfma_f32_16x16x32_bf16(pa1, v1, O[dt], 0, 0, 0);
        }
        if (c + 8 < 33) { STAGE_WRITE(cur ^ 1) }
        __syncthreads();
        cur ^= 1;
    }

    DUMP(qtB)    // curB==1 always on exit
#undef STAGE_ISSUE
#undef STAGE_WRITE
#undef LOADQ
#undef DUMP
#undef RESET_STATE
}

// ---------------------------------------------------------------------------
// Kernel 3: out = Σ_s Opart[s] / Σ_s lpart[s].  bf16 partial reads, fp32
// accumulate, float4 x2 stores.  131072 threads.
// ---------------------------------------------------------------------------
__global__ __launch_bounds__(256) void merge_kernel(
    const ushort* __restrict__ Opart, const float* __restrict__ lpart,
    float* __restrict__ out)
{
    const int idx = blockIdx.x * 256 + threadIdx.x;    // 0..131071
    const int row = idx >> 3;
    float acc[8] = {0.f, 0.f, 0.f, 0.f, 0.f, 0.f, 0.f, 0.f};
    float lv = 0.f;
    #pragma unroll
    for (int s = 0; s < NSPLIT; ++s) {
        uint4 v = reinterpret_cast<const uint4*>(Opart + (size_t)s * NROWS * 64)[idx];
        const uint u0 = v.x, u1 = v.y, u2 = v.z, u3 = v.w;
        acc[0] += __uint_as_float((u0 & 0xffffu) << 16);
        acc[1] += __uint_as_float(u0 & 0xffff0000u);
        acc[2] += __uint_as_float((u1 & 0xffffu) << 16);
        acc[3] += __uint_as_float(u1 & 0xffff0000u);
        acc[4] += __uint_as_float((u2 & 0xffffu) << 16);
        acc[5] += __uint_as_float(u2 & 0xffff0000u);
        acc[6] += __uint_as_float((u3 & 0xffffu) << 16);
        acc[7] += __uint_as_float(u3 & 0xffff0000u);
        lv += lpart[s * NROWS + row];
    }
    const float inv = 1.0f / lv;
    float4 o0 = make_float4(acc[0] * inv, acc[1] * inv, acc[2] * inv, acc[3] * inv);
    float4 o1 = make_float4(acc[4] * inv, acc[5] * inv, acc[6] * inv, acc[7] * inv);
    reinterpret_cast<float4*>(out)[idx * 2]     = o0;
    reinterpret_cast<float4*>(out)[idx * 2 + 1] = o1;
}

extern "C" void kernel_launch(void* const* d_in, const int* in_sizes, int n_in,
                              void* d_out, int out_size, void* d_ws, size_t ws_size,
                              hipStream_t stream) {
    const float* x  = (const float*)d_in[0];
    const float* Wq = (const float*)d_in[1];
    const float* Wk = (const float*)d_in[2];
    const float* Wv = (const float*)d_in[3];
    float* out = (float*)d_out;

    ushort* qb   = (ushort*)d_ws;                    // 2MB
    ushort* kbuf = qb + (size_t)NROWS * 64;          // 2MB
    ushort* vt   = kbuf + (size_t)NROWS * 64;        // 2MB (transposed V)
    ushort* wp   = vt + (size_t)NROWS * 64;          // 384KB packed W^T
    float* lpart = (float*)(wp + 192 * 1024);        // 512KB  8 x row-sums
    ushort* Opart = (ushort*)(lpart + (size_t)NSPLIT * NROWS);  // 16MB  8 x bf16 O partials

    wpack_kernel<<<24, 256, 0, stream>>>(Wq, Wk, Wv, wp);
    // MEASUREMENT: qkv_gemm launched twice (idempotent).  The second launch
    // adds exactly one gemm-duration to the total: gemm = Tnew - 51.4us.
    qkv_gemm<<<NROWS / 32, 512, 0, stream>>>(x, wp, qb, kbuf, vt);
    qkv_gemm<<<NROWS / 32, 512, 0, stream>>>(x, wp, qb, kbuf, vt);
    attn_flash<<<1024, 256, 0, stream>>>(qb, kbuf, vt, Opart, lpart);
    merge_kernel<<<(NROWS * HDIM / 8) / 256, 256, 0, stream>>>(Opart, lpart, out);
}

// Round 19
// 52.436 us; speedup vs baseline: 3.3858x; 1.3106x over previous
//
#include <hip/hip_runtime.h>
#include <hip/hip_bf16.h>

#define BATCH 8
#define SEQ   2048
#define CDIM  1024
#define HDIM  64
#define NROWS (BATCH*SEQ)   // 16384
#define NSPLIT 8

typedef __attribute__((ext_vector_type(8))) short bf16x8;
typedef __attribute__((ext_vector_type(4))) float f32x4;

// 0.125 (1/sqrt(64)) * log2(e) — folded into Wq so QK^T emerges in exp2 units
#define QSCALE 0.18033688011112042f
// fixed softmax shift (exp2 units): scores bounded ~±8 << 24.  softmax is
// shift-invariant -> partials ADDITIVE (validated R6-R18: absmax 0.0156) ->
// cross-block merge = plain sums over per-split buffers.
#define SFIX 24.0f

__device__ inline ushort f2bf(float f) {
    union { float f; uint u; } x; x.f = f;
    uint r = (x.u + 0x7fffu + ((x.u >> 16) & 1u)) >> 16;
    return (ushort)r;
}

// async global->LDS, 16B per lane: HW writes lane l's data at lds_base + l*16
// (wave-uniform base).  Source address is per-lane.
__device__ inline void gload_lds16(const void* gsrc, void* ldst) {
    __builtin_amdgcn_global_load_lds(
        (const __attribute__((address_space(1))) unsigned int*)gsrc,
        (__attribute__((address_space(3))) unsigned int*)ldst,
        16, 0, 0);
}

// ---------------------------------------------------------------------------
// Kernel 0: pack W^T into the PRE-SWIZZLED linear chunk order wp3 so the
// GEMM's W staging is a bare global_load_lds (linear LDS dest + inverse-
// swizzled source == swizzled read; rule-21-compliant m173 pattern).
// Chunk (s, i): LDS linear byte i*16 of step s's ws tile must hold
// W^T[n = i>>3][c0 .. c0+7], c0 = (((i&7)*16) ^ ((n&7)<<4))/2 + s*64.
// 24576 chunks; thread g writes one 16B chunk.
// ---------------------------------------------------------------------------
__global__ __launch_bounds__(256) void wpack_kernel(
    const float* __restrict__ Wq, const float* __restrict__ Wk,
    const float* __restrict__ Wv, ushort* __restrict__ wp3)
{
    const int g = blockIdx.x * 256 + threadIdx.x;   // 0..24575
    const int s = g / 1536;                         // K-step 0..15
    const int i = g % 1536;                         // chunk within step
    const int n = i >> 3;                           // 0..191
    const int b0 = ((i & 7) * 16) ^ ((n & 7) << 4);
    const int c0 = s * 64 + (b0 >> 1);              // first of 8 ushorts
    const int which = n >> 6, nl = n & 63;
    const float* W = (which == 0) ? Wq : (which == 1) ? Wk : Wv;
    const float sc = (which == 0) ? QSCALE : 1.0f;

    ushort v[8];
    #pragma unroll
    for (int k = 0; k < 8; ++k)
        v[k] = f2bf(W[(size_t)(c0 + k) * HDIM + nl] * sc);
    uint4 pack;
    pack.x = (uint)v[0] | ((uint)v[1] << 16);
    pack.y = (uint)v[2] | ((uint)v[3] << 16);
    pack.z = (uint)v[4] | ((uint)v[5] << 16);
    pack.w = (uint)v[6] | ((uint)v[7] << 16);
    reinterpret_cast<uint4*>(wp3)[g] = pack;
}

// ---------------------------------------------------------------------------
// Kernel 1: QKV GEMM — R13 structure, ONE change: W staging via async
// global_load_lds (3 instrs/thread/step, no VGPR round-trip, no ds_writes)
// from the pre-permuted wp3.  x stays reg-staged (fp32->bf16 conversion).
// The __syncthreads vmcnt(0) drain now guarantees gload arrival (issued one
// full MFMA phase before consumption).  BM=32 -> 512 blocks; 512 thr.
// ---------------------------------------------------------------------------
__global__ __launch_bounds__(512, 4) void qkv_gemm(
    const float* __restrict__ x, const ushort* __restrict__ wp3,
    ushort* __restrict__ qb, ushort* __restrict__ kbuf, ushort* __restrict__ vt)
{
    __shared__ ushort xs[2][32 * 64];    // 8KB   [row][c] bf16, XOR-swizzled
    __shared__ ushort ws[2][192 * 64];   // 48KB  [n][c]  bf16, XOR-swizzled
    const int t = threadIdx.x;
    const int w = t >> 6, lane = t & 63;
    const int l15 = lane & 15, hi = lane >> 4;
    const int rowg = w & 1, colg = w >> 1;
    const int m0 = blockIdx.x * 32;

    f32x4 acc[3];
    #pragma unroll
    for (int i = 0; i < 3; ++i) acc[i] = (f32x4){0.f, 0.f, 0.f, 0.f};

    const int xrow = t >> 4, xc4 = t & 15;
    float4 xra, xrb;

#define GLOADW(STEP, BUF)                                                      \
    {                                                                          \
        _Pragma("unroll")                                                      \
        for (int j = 0; j < 3; ++j) {                                          \
            const int chunk = j * 512 + w * 64;                                \
            gload_lds16(wp3 + ((size_t)(STEP) * 1536 + chunk + lane) * 8,      \
                        reinterpret_cast<char*>(ws[BUF]) + chunk * 16);        \
        }                                                                      \
    }

#define LOADX(S, KK)                                                           \
    xr##S = reinterpret_cast<const float4*>(x + (size_t)(m0 + xrow) * CDIM + (KK))[xc4];

#define WRITEX(S, BUF)                                                         \
    {                                                                          \
        ushort4 bx = make_ushort4(f2bf(xr##S.x), f2bf(xr##S.y), f2bf(xr##S.z), f2bf(xr##S.w)); \
        int xb = (xrow * 128 + xc4 * 8) ^ ((xrow & 7) << 4);                   \
        *reinterpret_cast<ushort4*>(reinterpret_cast<char*>(xs[BUF]) + xb) = bx; \
    }

#define MFMA_STEP(BUF)                                                         \
    {                                                                          \
        const int arow = rowg * 16 + l15;                                      \
        _Pragma("unroll")                                                      \
        for (int c32 = 0; c32 < 2; ++c32) {                                    \
            const int abyte = (arow * 128 + hi * 16 + c32 * 64) ^ ((arow & 7) << 4); \
            bf16x8 a = *reinterpret_cast<const bf16x8*>(reinterpret_cast<char*>(xs[BUF]) + abyte); \
            _Pragma("unroll")                                                  \
            for (int nf = 0; nf < 3; ++nf) {                                   \
                const int n = colg * 48 + nf * 16 + l15;                       \
                const int bbyte = (n * 128 + hi * 16 + c32 * 64) ^ ((n & 7) << 4); \
                bf16x8 b = *reinterpret_cast<const bf16x8*>(reinterpret_cast<char*>(ws[BUF]) + bbyte); \
                acc[nf] = __builtin_amdgcn_mfma_f32_16x16x32_bf16(a, b, acc[nf], 0, 0, 0); \
            }                                                                  \
        }                                                                      \
    }

    // prologue: W steps 0,1 async -> ws[0],ws[1]; x step 0 staged, step 1 in regs
    GLOADW(0, 0)
    GLOADW(1, 1)
    LOADX(a, 0)
    LOADX(b, 64)
    WRITEX(a, 0)
    __syncthreads();                     // vmcnt(0): ws[0],ws[1] resident

    for (int step = 0; step < 16; step += 2) {
        if (step + 2 < 16) { LOADX(a, (step + 2) * 64) }
        MFMA_STEP(0)                     // reads ws[0], xs[0]
        WRITEX(b, 1)
        __syncthreads();                 // all done with ws[0]; xs[1],ws[1] ready
        if (step + 2 < 16) { GLOADW(step + 2, 0) }   // one MFMA phase of cover
        if (step + 3 < 16) { LOADX(b, (step + 3) * 64) }
        MFMA_STEP(1)                     // reads ws[1], xs[1]
        if (step + 2 < 16) { WRITEX(a, 0) }
        __syncthreads();                 // drains GLOADW(step+2) + ds ops
        if (step + 3 < 16) { GLOADW(step + 3, 1) }
    }
#undef GLOADW
#undef LOADX
#undef WRITEX
#undef MFMA_STEP

    // epilogue: C layout col = l15 (n), row = hi*4 + r
    #pragma unroll
    for (int nf = 0; nf < 3; ++nf) {
        const int n = colg * 48 + nf * 16 + l15;
        #pragma unroll
        for (int r = 0; r < 4; ++r) {
            const int grow = m0 + rowg * 16 + hi * 4 + r;
            const ushort bv = f2bf(acc[nf][r]);
            if (n < 64) {
                qb[(size_t)grow * 64 + n] = bv;
            } else if (n < 128) {
                kbuf[(size_t)grow * 64 + (n - 64)] = bv;
            } else {
                const int b = grow >> 11, tt = grow & 2047;
                vt[(((size_t)b * 64 + (n - 128)) << 11) + tt] = bv;
            }
        }
    }
}

// ---------------------------------------------------------------------------
// Kernel 2: flash attention, LDS-shared K/V (R13 exact; 16.6us measured).
// ---------------------------------------------------------------------------
__global__ __launch_bounds__(256, 4) void attn_flash(
    const ushort* __restrict__ qb, const ushort* __restrict__ kbuf,
    const ushort* __restrict__ vt, ushort* __restrict__ Opart,
    float* __restrict__ lpart)
{
    __shared__ ushort kst[2][64 * 64];   // 16KB  K tile, XOR-swizzled
    __shared__ ushort vst[2][64 * 64];   // 16KB  V tile (vt layout [d][t])
    __shared__ ushort P[4][1024];        // 8KB   per-wave P round-trip

    const int t = threadIdx.x;
    const int w = t >> 6, lane = t & 63;
    const int l15 = lane & 15, hi = lane >> 4;
    const int bid = blockIdx.x;
    const int pid = (bid & 7) * 128 + (bid >> 3);   // XCD x -> batch x
    const int batch = pid >> 7;
    const int rem = pid & 127;
    const int pairIdx = rem >> 3;        // 0..15
    const int s = rem & 7;               // split 0..7
    const int qtA = pairIdx, qtB = 31 - pairIdx;    // 64-row q-tiles
    const int ntA = qtA + 1;             // ntA + ntB == 33

    const ushort* kB = kbuf + (size_t)batch * SEQ * 64;
    const ushort* vB = vt + (size_t)batch * 64 * SEQ;
    ushort* Osp = Opart + (size_t)s * NROWS * 64;
    float* lsp = lpart + (size_t)s * NROWS;
    char* pw = reinterpret_cast<char*>(P[w]);

    const int r0 = t >> 3, c8 = t & 7;   // chunk0 row 0..31
    const int r1 = r0 + 32;              // chunk1 row 32..63
    const int sb0 = (r0 * 128 + c8 * 16) ^ ((r0 & 7) << 4);
    const int sb1 = (r1 * 128 + c8 * 16) ^ ((r1 & 7) << 4);

    uint4 kr0, kr1, vr0, vr1;

#define STAGE_ISSUE(C)                                                        \
    {                                                                         \
        const int kt_ = ((C) >= ntA) ? ((C) - ntA) : (C);                     \
        const int j0_ = kt_ * 64;                                             \
        kr0 = *reinterpret_cast<const uint4*>(kB + (size_t)(j0_ + r0) * 64 + c8 * 8); \
        kr1 = *reinterpret_cast<const uint4*>(kB + (size_t)(j0_ + r1) * 64 + c8 * 8); \
        vr0 = *reinterpret_cast<const uint4*>(vB + (size_t)r0 * SEQ + j0_ + c8 * 8);  \
        vr1 = *reinterpret_cast<const uint4*>(vB + (size_t)r1 * SEQ + j0_ + c8 * 8);  \
    }

#define STAGE_WRITE(BUF)                                                      \
    {                                                                         \
        *reinterpret_cast<uint4*>(reinterpret_cast<char*>(kst[BUF]) + sb0) = kr0; \
        *reinterpret_cast<uint4*>(reinterpret_cast<char*>(kst[BUF]) + sb1) = kr1; \
        *reinterpret_cast<uint4*>(reinterpret_cast<char*>(vst[BUF]) + sb0) = vr0; \
        *reinterpret_cast<uint4*>(reinterpret_cast<char*>(vst[BUF]) + sb1) = vr1; \
    }

#define LOADQ(QT)                                                             \
    {                                                                         \
        const ushort* qp_ = qb + (size_t)(batch * SEQ + (QT) * 64 + w * 16 + l15) * 64 + hi * 8; \
        aq0 = *reinterpret_cast<const bf16x8*>(qp_);                          \
        aq1 = *reinterpret_cast<const bf16x8*>(qp_ + 32);                     \
    }

#define DUMP(QT)                                                              \
    {                                                                         \
        _Pragma("unroll")                                                     \
        for (int dt = 0; dt < 4; ++dt)                                        \
            _Pragma("unroll")                                                 \
            for (int r = 0; r < 4; ++r)                                       \
                Osp[(size_t)(batch * SEQ + (QT) * 64 + w * 16 + hi * 4 + r) * 64 + dt * 16 + l15] = f2bf(O[dt][r]); \
        _Pragma("unroll")                                                     \
        for (int r = 0; r < 4; ++r) {                                         \
            float s_ = lsum[r];                                               \
            s_ += __shfl_xor(s_, 1, 64);                                      \
            s_ += __shfl_xor(s_, 2, 64);                                      \
            s_ += __shfl_xor(s_, 4, 64);                                      \
            s_ += __shfl_xor(s_, 8, 64);                                      \
            if (l15 == 0)                                                     \
                lsp[batch * SEQ + (QT) * 64 + w * 16 + hi * 4 + r] = s_;      \
        }                                                                     \
    }

#define RESET_STATE()                                                         \
    {                                                                         \
        _Pragma("unroll")                                                     \
        for (int i = 0; i < 4; ++i) {                                         \
            O[i] = (f32x4){0.f, 0.f, 0.f, 0.f};                               \
            lsum[i] = 0.f;                                                    \
        }                                                                     \
    }

    bf16x8 aq0, aq1;
    LOADQ(qtA)
    f32x4 O[4];
    float lsum[4];
    RESET_STATE()

    STAGE_ISSUE(s)
    STAGE_WRITE(0)
    __syncthreads();

    int curB = 0, cur = 0;
    for (int c = s; c < 33; c += 8) {
        if (c + 8 < 33) { STAGE_ISSUE(c + 8) }    // in flight over compute
        if (c >= ntA && !curB) {                  // block-uniform A -> B
            DUMP(qtA)
            RESET_STATE()
            LOADQ(qtB)
            curB = 1;
        }
        const int qt = curB ? qtB : qtA;
        const int kt = curB ? (c - ntA) : c;
        const int j0 = kt * 64;
        const int qrow0 = qt * 64 + w * 16;
        const bool diag = curB ? (c == 32) : (c == ntA - 1);

        const char* kc = reinterpret_cast<const char*>(kst[cur]);
        const char* vc = reinterpret_cast<const char*>(vst[cur]);

        // ---- QK^T from LDS K ----
        f32x4 S[4];
        #pragma unroll
        for (int kb = 0; kb < 4; ++kb) {
            const int key = kb * 16 + l15;
            const int sw = (key & 7) << 4;
            bf16x8 b0 = *reinterpret_cast<const bf16x8*>(kc + ((key * 128 + hi * 16) ^ sw));
            bf16x8 b1 = *reinterpret_cast<const bf16x8*>(kc + ((key * 128 + hi * 16 + 64) ^ sw));
            f32x4 z = (f32x4){0.f, 0.f, 0.f, 0.f};
            z = __builtin_amdgcn_mfma_f32_16x16x32_bf16(aq0, b0, z, 0, 0, 0);
            z = __builtin_amdgcn_mfma_f32_16x16x32_bf16(aq1, b1, z, 0, 0, 0);
            S[kb] = z;
        }
        // ---- causal mask: only the diagonal tile ----
        if (diag) {
            #pragma unroll
            for (int kb = 0; kb < 4; ++kb) {
                const int key = j0 + kb * 16 + l15;
                #pragma unroll
                for (int r = 0; r < 4; ++r) {
                    const int qr = qrow0 + hi * 4 + r;
                    if (key > qr) S[kb][r] = -1e30f;
                }
            }
        }
        // ---- fixed-shift softmax ----
        #pragma unroll
        for (int kb = 0; kb < 4; ++kb)
            #pragma unroll
            for (int r = 0; r < 4; ++r)
                S[kb][r] = exp2f(S[kb][r] - SFIX);
        #pragma unroll
        for (int r = 0; r < 4; ++r)
            lsum[r] += (S[0][r] + S[1][r]) + (S[2][r] + S[3][r]);

        // ---- P: C-layout -> per-wave LDS (swizzled) -> A-layout ----
        #pragma unroll
        for (int kb = 0; kb < 4; ++kb) {
            #pragma unroll
            for (int r = 0; r < 4; ++r) {
                const int prow = hi * 4 + r;
                const int pcol = kb * 16 + l15;
                const int byte = (prow * 128 + pcol * 2) ^ ((prow & 7) << 4);
                *reinterpret_cast<ushort*>(pw + byte) = f2bf(S[kb][r]);
            }
        }
        asm volatile("" ::: "memory");   // intra-wave LDS in-order
        const int pb0 = (l15 * 128 + hi * 16) ^ ((l15 & 7) << 4);
        const int pb1 = (l15 * 128 + hi * 16 + 64) ^ ((l15 & 7) << 4);
        bf16x8 pa0 = *reinterpret_cast<const bf16x8*>(pw + pb0);
        bf16x8 pa1 = *reinterpret_cast<const bf16x8*>(pw + pb1);
        // ---- PV from LDS V ----
        #pragma unroll
        for (int dt = 0; dt < 4; ++dt) {
            const int d = dt * 16 + l15;
            const int sw = (d & 7) << 4;
            bf16x8 v0 = *reinterpret_cast<const bf16x8*>(vc + ((d * 128 + hi * 16) ^ sw));
            bf16x8 v1 = *reinterpret_cast<const bf16x8*>(vc + ((d * 128 + hi * 16 + 64) ^ sw));
            O[dt] = __builtin_amdgcn_mfma_f32_16x16x32_bf16(pa0, v0, O[dt], 0, 0, 0);
            O[dt] = __builtin_amdgcn_mfma_f32_16x16x32_bf16(pa1, v1, O[dt], 0, 0, 0);
        }
        if (c + 8 < 33) { STAGE_WRITE(cur ^ 1) }
        __syncthreads();
        cur ^= 1;
    }

    DUMP(qtB)    // curB==1 always on exit
#undef STAGE_ISSUE
#undef STAGE_WRITE
#undef LOADQ
#undef DUMP
#undef RESET_STATE
}

// ---------------------------------------------------------------------------
// Kernel 3: out = Σ_s Opart[s] / Σ_s lpart[s].  bf16 partial reads, fp32
// accumulate, float4 x2 stores.  131072 threads.
// ---------------------------------------------------------------------------
__global__ __launch_bounds__(256) void merge_kernel(
    const ushort* __restrict__ Opart, const float* __restrict__ lpart,
    float* __restrict__ out)
{
    const int idx = blockIdx.x * 256 + threadIdx.x;    // 0..131071
    const int row = idx >> 3;
    float acc[8] = {0.f, 0.f, 0.f, 0.f, 0.f, 0.f, 0.f, 0.f};
    float lv = 0.f;
    #pragma unroll
    for (int s = 0; s < NSPLIT; ++s) {
        uint4 v = reinterpret_cast<const uint4*>(Opart + (size_t)s * NROWS * 64)[idx];
        const uint u0 = v.x, u1 = v.y, u2 = v.z, u3 = v.w;
        acc[0] += __uint_as_float((u0 & 0xffffu) << 16);
        acc[1] += __uint_as_float(u0 & 0xffff0000u);
        acc[2] += __uint_as_float((u1 & 0xffffu) << 16);
        acc[3] += __uint_as_float(u1 & 0xffff0000u);
        acc[4] += __uint_as_float((u2 & 0xffffu) << 16);
        acc[5] += __uint_as_float(u2 & 0xffff0000u);
        acc[6] += __uint_as_float((u3 & 0xffffu) << 16);
        acc[7] += __uint_as_float(u3 & 0xffff0000u);
        lv += lpart[s * NROWS + row];
    }
    const float inv = 1.0f / lv;
    float4 o0 = make_float4(acc[0] * inv, acc[1] * inv, acc[2] * inv, acc[3] * inv);
    float4 o1 = make_float4(acc[4] * inv, acc[5] * inv, acc[6] * inv, acc[7] * inv);
    reinterpret_cast<float4*>(out)[idx * 2]     = o0;
    reinterpret_cast<float4*>(out)[idx * 2 + 1] = o1;
}

extern "C" void kernel_launch(void* const* d_in, const int* in_sizes, int n_in,
                              void* d_out, int out_size, void* d_ws, size_t ws_size,
                              hipStream_t stream) {
    const float* x  = (const float*)d_in[0];
    const float* Wq = (const float*)d_in[1];
    const float* Wk = (const float*)d_in[2];
    const float* Wv = (const float*)d_in[3];
    float* out = (float*)d_out;

    ushort* qb   = (ushort*)d_ws;                    // 2MB
    ushort* kbuf = qb + (size_t)NROWS * 64;          // 2MB
    ushort* vt   = kbuf + (size_t)NROWS * 64;        // 2MB (transposed V)
    ushort* wp3  = vt + (size_t)NROWS * 64;          // 384KB pre-swizzled W chunks
    float* lpart = (float*)(wp3 + 192 * 1024);       // 512KB  8 x row-sums
    ushort* Opart = (ushort*)(lpart + (size_t)NSPLIT * NROWS);  // 16MB  8 x bf16 O partials

    wpack_kernel<<<96, 256, 0, stream>>>(Wq, Wk, Wv, wp3);
    qkv_gemm<<<NROWS / 32, 512, 0, stream>>>(x, wp3, qb, kbuf, vt);
    attn_flash<<<1024, 256, 0, stream>>>(qb, kbuf, vt, Opart, lpart);
    merge_kernel<<<(NROWS * HDIM / 8) / 256, 256, 0, stream>>>(Opart, lpart, out);
}